// Round 3
// baseline (1267.626 us; speedup 1.0000x reference)
//
#include <hip/hip_runtime.h>
#include <stdint.h>

typedef unsigned short u16;
typedef __attribute__((ext_vector_type(8))) __bf16 bf16x8;
typedef __attribute__((ext_vector_type(8))) u16 u16x8;
typedef __attribute__((ext_vector_type(4))) u16 u16x4;
typedef __attribute__((ext_vector_type(4))) float f32x4;

#define LAM 0.95f
#define DISCOUNT (1.0f - 1.0f / 333.0f)

constexpr int Bsz = 1024, Tsz = 16, Dsz = 5120, Hsz = 1024;
constexpr int Msz = Bsz * Tsz;   // 16384
constexpr int Nsz = 2 * Hsz;     // 2048 (net | slow concat on N)
constexpr int ES = 136;          // epilogue LDS tile stride (u16)

// ---------- helpers ----------
__device__ __forceinline__ u16 f2bf(float x) {
  union { float f; uint32_t u; } un; un.f = x;
  uint32_t u = un.u;
  return (u16)((u + 0x7FFFu + ((u >> 16) & 1u)) >> 16);  // RNE
}
__device__ __forceinline__ void async16(const void* g, void* l) {
  __builtin_amdgcn_global_load_lds(
      (const __attribute__((address_space(1))) uint32_t*)g,
      (__attribute__((address_space(3))) uint32_t*)l, 16, 0, 0);
}

// ---------- transpose + convert: src fp32 [K][N] -> dst bf16 [N][K] ----------
__global__ __launch_bounds__(256) void transpose_cvt(
    const float* __restrict__ src, u16* __restrict__ dst, int K, int N) {
  __shared__ float tile[64][65];
  int k0 = blockIdx.x * 64, n0 = blockIdx.y * 64;
  int tid = threadIdx.x;
#pragma unroll
  for (int i = 0; i < 4; ++i) {
    int idx = i * 256 + tid, rr = idx >> 4, c4 = (idx & 15) * 4;
    float4 v = *(const float4*)&src[(size_t)(k0 + rr) * N + n0 + c4];
    tile[rr][c4 + 0] = v.x; tile[rr][c4 + 1] = v.y;
    tile[rr][c4 + 2] = v.z; tile[rr][c4 + 3] = v.w;
  }
  __syncthreads();
#pragma unroll
  for (int i = 0; i < 4; ++i) {
    int idx = i * 256 + tid, rr = idx >> 4, c4 = (idx & 15) * 4;
    u16x4 o;
    o[0] = f2bf(tile[c4 + 0][rr]); o[1] = f2bf(tile[c4 + 1][rr]);
    o[2] = f2bf(tile[c4 + 2][rr]); o[3] = f2bf(tile[c4 + 3][rr]);
    *(u16x4*)&dst[(size_t)(n0 + rr) * K + k0 + c4] = o;
  }
}

// ---------- small prep: bias/w3 concat + zero head accumulators ----------
__global__ void prep_small(const float* nb1, const float* sb1, const float* nb2,
                           const float* sb2, const float* nw3, const float* sw3,
                           float* bias1, float* bias2, float* w3cat,
                           float* accN, float* accS) {
  int i = blockIdx.x * 256 + threadIdx.x;
  if (i < 1024) { bias1[i] = nb1[i]; bias2[i] = nb2[i]; w3cat[i] = nw3[i]; }
  else if (i < 2048) { bias1[i] = sb1[i - 1024]; bias2[i] = sb2[i - 1024]; w3cat[i] = sw3[i - 1024]; }
  for (int j = i; j < Msz; j += gridDim.x * 256) { accN[j] = 0.f; accS[j] = 0.f; }
}

// ---------- fp32 -> bf16 elementwise (feat pre-convert) ----------
__global__ void cvt_f32_to_bf16(const float* __restrict__ src, u16* __restrict__ dst, int n4) {
  int i = blockIdx.x * 256 + threadIdx.x;
  int stride = gridDim.x * 256;
  for (; i < n4; i += stride) {
    float4 v = ((const float4*)src)[i];
    u16x4 o; o[0] = f2bf(v.x); o[1] = f2bf(v.y); o[2] = f2bf(v.z); o[3] = f2bf(v.w);
    ((u16x4*)dst)[i] = o;
  }
}

// ---------- GEMM1: 256x128 tile, 4 waves of 128x64, bf16 A via global_load_lds ----------
// Out[m][n] = bf16(silu(A·B^T + bias)); operand-swapped MFMA:
// lane value (a,b,rr): row m = wm+a*16+(lane&15), col n = wn+b*16+(lane>>4)*4+rr
__global__ __launch_bounds__(256) void gemm1_k(
    const u16* __restrict__ Ap, const u16* __restrict__ Bp,
    const float* __restrict__ bias, u16* __restrict__ Out, int K) {
  __shared__ __align__(16) u16 smem[24576];   // 48 KB: A 256x64 | B 128x64
  u16* ldsA = smem;
  u16* ldsB = smem + 16384;

  const int tid = threadIdx.x;
  const int lane = tid & 63;
  const int wv = tid >> 6;
  const int wm = (wv >> 1) * 128;  // wave row offset (0 or 128)
  const int wn = (wv & 1) * 64;    // wave col offset (0 or 64)
  const int lm = lane & 15, lq = lane >> 4, l7 = lane & 7;

  // XCD-pinned: xcd = blk&7 owns 8 M-tiles x 16 N-tiles, walked in 8x8 halves
  const int blk = blockIdx.x;          // 0..1023
  const int xcd = blk & 7;
  const int l = blk >> 3;              // 0..127
  const int half_ = l >> 6;            // 0..1
  const int mi = l & 7, ni = (l >> 3) & 7;
  const int m0 = (xcd * 8 + mi) << 8;              // 256-row tiles
  const int n0 = ((half_ << 3) + ni) << 7;         // 128-col tiles

  // staging: A 2048 chunks (8/thread), B 1024 chunks (4/thread); XOR swizzle
  const u16* asrc[8]; u16* ldsAd[8];
  const u16* bsrc[4]; u16* ldsBd[4];
#pragma unroll
  for (int i = 0; i < 8; ++i) {
    int cid = i * 256 + tid;
    int row = cid >> 3, ch = cid & 7;
    int kp = ch ^ (row & 7);
    asrc[i] = Ap + (size_t)(m0 + row) * K + kp * 8;
    ldsAd[i] = &ldsA[cid * 8];
  }
#pragma unroll
  for (int i = 0; i < 4; ++i) {
    int cid = i * 256 + tid;
    int row = cid >> 3, ch = cid & 7;
    int kp = ch ^ (row & 7);
    bsrc[i] = Bp + (size_t)(n0 + row) * K + kp * 8;
    ldsBd[i] = &ldsB[cid * 8];
  }

  int rA[8], rB[4];
#pragma unroll
  for (int t = 0; t < 8; ++t) rA[t] = (wm + t * 16 + lm) * 64;
#pragma unroll
  for (int t = 0; t < 4; ++t) rB[t] = (wn + t * 16 + lm) * 64;

  f32x4 acc[8][4];
#pragma unroll
  for (int a = 0; a < 8; ++a)
#pragma unroll
    for (int b = 0; b < 4; ++b) acc[a][b] = f32x4{0.f, 0.f, 0.f, 0.f};

  for (int kt = 0; kt < K; kt += 64) {
#pragma unroll
    for (int i = 0; i < 4; ++i) async16(bsrc[i] + kt, ldsBd[i]);
#pragma unroll
    for (int i = 0; i < 8; ++i) async16(asrc[i] + kt, ldsAd[i]);
    __syncthreads();
#pragma unroll
    for (int ks = 0; ks < 2; ++ks) {
      const int ck = ((ks << 2) + lq) ^ l7;
      bf16x8 bfr[4];
#pragma unroll
      for (int t = 0; t < 4; ++t) bfr[t] = *(const bf16x8*)&ldsB[rB[t] + ck * 8];
#pragma unroll
      for (int h = 0; h < 2; ++h) {
        bf16x8 af[4];
#pragma unroll
        for (int t = 0; t < 4; ++t) af[t] = *(const bf16x8*)&ldsA[rA[h * 4 + t] + ck * 8];
#pragma unroll
        for (int a = 0; a < 4; ++a)
#pragma unroll
          for (int b = 0; b < 4; ++b)
            acc[h * 4 + a][b] =
                __builtin_amdgcn_mfma_f32_16x16x32_bf16(bfr[b], af[a], acc[h * 4 + a][b], 0, 0, 0);
      }
    }
    __syncthreads();
  }

  // epilogue: two 128-row passes through the 48 KB smem, coalesced 16B stores
#pragma unroll
  for (int p = 0; p < 2; ++p) {
    if ((wv >> 1) == p) {
#pragma unroll
      for (int a = 0; a < 8; ++a) {
        int ml = a * 16 + lm;
#pragma unroll
        for (int b = 0; b < 4; ++b) {
          int nb = wn + b * 16 + lq * 4;
          u16x4 pk;
#pragma unroll
          for (int rr = 0; rr < 4; ++rr) {
            float v = acc[a][b][rr] + bias[n0 + nb + rr];
            v = v * (1.0f / (1.0f + __expf(-v)));
            pk[rr] = f2bf(v);
          }
          *(u16x4*)&smem[ml * ES + nb] = pk;
        }
      }
    }
    __syncthreads();
#pragma unroll
    for (int i = 0; i < 8; ++i) {
      int r = i * 16 + (tid >> 4);
      int c = (tid & 15) * 8;
      u16x8 vv = *(const u16x8*)&smem[r * ES + c];
      *(u16x8*)&Out[(size_t)(m0 + p * 128 + r) * Nsz + n0 + c] = vv;
    }
    __syncthreads();
  }
}

// ---------- GEMM2 (+fused w3 head): 128x128 tile, 4 waves of 64x64 ----------
template <int MODE, bool A_F32>
__global__ __launch_bounds__(256) void gemm_fused(
    const void* __restrict__ Ap, const u16* __restrict__ Bp,
    const float* __restrict__ bias, u16* __restrict__ Out,
    const float* __restrict__ w3cat, float* __restrict__ accN, float* __restrict__ accS,
    int K, int lda, int a_half_off) {
  __shared__ __align__(16) u16 smem[(MODE == 0) ? (128 * ES) : 16384];
  u16* ldsA = smem;
  u16* ldsB = smem + 8192;

  const int tid = threadIdx.x;
  const int lane = tid & 63;
  const int wv = tid >> 6;
  const int wm = (wv >> 1) << 6;
  const int wn = (wv & 1) << 6;
  const int lm = lane & 15, lq = lane >> 4, l7 = lane & 7;

  const int blk = blockIdx.x;
  const int xcd = blk & 7;
  const int l = blk >> 3;
  const int quad = l >> 6;
  const int mi = l & 7, ni = (l >> 3) & 7;
  const int mt = xcd * 16 + ((quad & 1) << 3) + mi;
  const int nt = ((quad >> 1) << 3) + ni;
  const int m0 = mt << 7, n0 = nt << 7;
  const int a_off = (n0 >= Hsz) ? a_half_off : 0;

  const u16* bsrc[4];
  const float* asrcf[4];
  const u16* asrcb[4];
  u16* ldsAd[4];
  u16* ldsBd[4];
#pragma unroll
  for (int i = 0; i < 4; ++i) {
    int cid = i * 256 + tid;
    int row = cid >> 3, ch = cid & 7;
    int kp = ch ^ (row & 7);
    bsrc[i] = Bp + (size_t)(n0 + row) * K + kp * 8;
    if (A_F32) asrcf[i] = (const float*)Ap + (size_t)(m0 + row) * lda + a_off + kp * 8;
    else       asrcb[i] = (const u16*)Ap + (size_t)(m0 + row) * lda + a_off + kp * 8;
    ldsAd[i] = &ldsA[cid * 8];
    ldsBd[i] = &ldsB[cid * 8];
  }

  int rA[4], rB[4];
#pragma unroll
  for (int t = 0; t < 4; ++t) {
    rA[t] = (wm + t * 16 + lm) * 64;
    rB[t] = (wn + t * 16 + lm) * 64;
  }

  f32x4 acc[4][4];
#pragma unroll
  for (int a = 0; a < 4; ++a)
#pragma unroll
    for (int b = 0; b < 4; ++b) acc[a][b] = f32x4{0.f, 0.f, 0.f, 0.f};

  for (int kt = 0; kt < K; kt += 64) {
#pragma unroll
    for (int i = 0; i < 4; ++i) async16(bsrc[i] + kt, ldsBd[i]);
    if (A_F32) {
      float4 v0[4], v1[4];
#pragma unroll
      for (int i = 0; i < 4; ++i) {
        const float* p = asrcf[i] + kt;
        v0[i] = *(const float4*)p;
        v1[i] = *(const float4*)(p + 4);
      }
#pragma unroll
      for (int i = 0; i < 4; ++i) {
        u16x8 pk;
        pk[0] = f2bf(v0[i].x); pk[1] = f2bf(v0[i].y); pk[2] = f2bf(v0[i].z); pk[3] = f2bf(v0[i].w);
        pk[4] = f2bf(v1[i].x); pk[5] = f2bf(v1[i].y); pk[6] = f2bf(v1[i].z); pk[7] = f2bf(v1[i].w);
        *(u16x8*)ldsAd[i] = pk;
      }
    } else {
#pragma unroll
      for (int i = 0; i < 4; ++i) async16(asrcb[i] + kt, ldsAd[i]);
    }
    __syncthreads();
#pragma unroll
    for (int ks = 0; ks < 2; ++ks) {
      const int ck = ((ks << 2) + lq) ^ l7;
      bf16x8 af[4], bfr[4];
#pragma unroll
      for (int t = 0; t < 4; ++t) af[t] = *(const bf16x8*)&ldsA[rA[t] + ck * 8];
#pragma unroll
      for (int t = 0; t < 4; ++t) bfr[t] = *(const bf16x8*)&ldsB[rB[t] + ck * 8];
#pragma unroll
      for (int a = 0; a < 4; ++a)
#pragma unroll
        for (int b = 0; b < 4; ++b)
          acc[a][b] = __builtin_amdgcn_mfma_f32_16x16x32_bf16(bfr[b], af[a], acc[a][b], 0, 0, 0);
    }
    __syncthreads();
  }

  if (MODE == 0) {
#pragma unroll
    for (int a = 0; a < 4; ++a) {
      int ml = wm + a * 16 + lm;
#pragma unroll
      for (int b = 0; b < 4; ++b) {
        int nb = wn + b * 16 + lq * 4;
        u16x4 pk;
#pragma unroll
        for (int rr = 0; rr < 4; ++rr) {
          float v = acc[a][b][rr] + bias[n0 + nb + rr];
          v = v * (1.0f / (1.0f + __expf(-v)));
          pk[rr] = f2bf(v);
        }
        *(u16x4*)&smem[ml * ES + nb] = pk;
      }
    }
    __syncthreads();
#pragma unroll
    for (int i = 0; i < 8; ++i) {
      int r = i * 16 + (tid >> 4);
      int c = (tid & 15) * 8;
      u16x8 vv = *(const u16x8*)&smem[r * ES + c];
      *(u16x8*)&Out[(size_t)(m0 + r) * Nsz + n0 + c] = vv;
    }
  } else {
    float pr[4] = {0.f, 0.f, 0.f, 0.f};
#pragma unroll
    for (int a = 0; a < 4; ++a) {
#pragma unroll
      for (int b = 0; b < 4; ++b) {
        int nb = n0 + wn + b * 16 + lq * 4;
#pragma unroll
        for (int rr = 0; rr < 4; ++rr) {
          float v = acc[a][b][rr] + bias[nb + rr];
          v = v * (1.0f / (1.0f + __expf(-v)));
          pr[a] += v * w3cat[nb + rr];
        }
      }
    }
    float* accp = (n0 < Hsz) ? accN : accS;
#pragma unroll
    for (int a = 0; a < 4; ++a) {
      pr[a] += __shfl_xor(pr[a], 16);
      pr[a] += __shfl_xor(pr[a], 32);
      if (lq == 0) atomicAdd(&accp[m0 + wm + a * 16 + lm], pr[a]);
    }
  }
}

// ---------- finalize + per-batch lambda-return scan ----------
__global__ void finalize_scan(const float* __restrict__ accN, const float* __restrict__ accS,
                              const float* __restrict__ nb3, const float* __restrict__ sb3,
                              const float* __restrict__ voff, const float* __restrict__ vscl,
                              const float* __restrict__ rew, const float* __restrict__ cont,
                              float* __restrict__ o_rew, float* __restrict__ o_ret,
                              float* __restrict__ o_tar, float* __restrict__ o_cri,
                              float* __restrict__ o_slo) {
  __shared__ float star[Tsz], srew[Tsz], scont[Tsz];
  int b = blockIdx.x;
  int t = threadIdx.x;
  if (t < Tsz) {
    int m = b * Tsz + t;
    float c = accN[m] + nb3[0];
    float s = accS[m] + sb3[0];
    float tv = s * vscl[0] + voff[0];
    o_cri[m] = c; o_slo[m] = s; o_tar[m] = tv;
    float rw = rew[m];
    o_rew[m] = rw;
    star[t] = tv; srew[t] = rw; scont[t] = cont[m];
  }
  __syncthreads();
  if (t == 0) {
    float carry = star[Tsz - 1];
    for (int k = Tsz - 2; k >= 0; --k) {
      float d = scont[k + 1] * DISCOUNT;
      carry = srew[k + 1] + (1.0f - LAM) * d * star[k + 1] + d * LAM * carry;
      o_ret[b * (Tsz - 1) + k] = carry;
    }
  }
}

// ---------- workspace layout ----------
constexpr size_t WT1_OFF = 0;
constexpr size_t WT1_BYTES = (size_t)Nsz * Dsz * 2;
constexpr size_t WT2_OFF = WT1_OFF + WT1_BYTES;
constexpr size_t WT2_BYTES = (size_t)Nsz * Hsz * 2;
constexpr size_t B1_OFF = WT2_OFF + WT2_BYTES;
constexpr size_t B2_OFF = B1_OFF + 8192;
constexpr size_t W3_OFF = B2_OFF + 8192;
constexpr size_t ACCN_OFF = W3_OFF + 8192;
constexpr size_t ACCS_OFF = ACCN_OFF + (size_t)Msz * 4;
constexpr size_t H1_OFF = ACCS_OFF + (size_t)Msz * 4;
constexpr size_t H_BYTES = (size_t)Msz * Nsz * 2;
constexpr size_t FEATB_OFF = H1_OFF + H_BYTES;
constexpr size_t FEATB_BYTES = (size_t)Msz * Dsz * 2;
constexpr size_t NEED_BIG = FEATB_OFF + FEATB_BYTES;

extern "C" void kernel_launch(void* const* d_in, const int* in_sizes, int n_in,
                              void* d_out, int out_size, void* d_ws, size_t ws_size,
                              hipStream_t stream) {
  const float* feat = (const float*)d_in[0];
  const float* rew  = (const float*)d_in[1];
  const float* cont = (const float*)d_in[2];
  const float* nw1  = (const float*)d_in[3];
  const float* nb1  = (const float*)d_in[4];
  const float* nw2  = (const float*)d_in[5];
  const float* nb2  = (const float*)d_in[6];
  const float* nw3  = (const float*)d_in[7];
  const float* nb3  = (const float*)d_in[8];
  const float* sw1  = (const float*)d_in[9];
  const float* sb1  = (const float*)d_in[10];
  const float* sw2  = (const float*)d_in[11];
  const float* sb2  = (const float*)d_in[12];
  const float* sw3  = (const float*)d_in[13];
  const float* sb3  = (const float*)d_in[14];
  const float* voff = (const float*)d_in[15];
  const float* vscl = (const float*)d_in[16];

  char* ws = (char*)d_ws;
  u16* wt1 = (u16*)(ws + WT1_OFF);
  u16* wt2 = (u16*)(ws + WT2_OFF);
  float* bias1 = (float*)(ws + B1_OFF);
  float* bias2 = (float*)(ws + B2_OFF);
  float* w3cat = (float*)(ws + W3_OFF);
  float* accN = (float*)(ws + ACCN_OFF);
  float* accS = (float*)(ws + ACCS_OFF);
  u16* h1 = (u16*)(ws + H1_OFF);
  u16* featb = (u16*)(ws + FEATB_OFF);
  const bool big = ws_size >= NEED_BIG;

  float* out = (float*)d_out;
  float* o_rew = out;
  float* o_ret = out + 16384;
  float* o_tar = out + 31744;
  float* o_cri = out + 48128;
  float* o_slo = out + 64512;

  transpose_cvt<<<dim3(Dsz / 64, Hsz / 64), 256, 0, stream>>>(nw1, wt1, Dsz, Hsz);
  transpose_cvt<<<dim3(Dsz / 64, Hsz / 64), 256, 0, stream>>>(sw1, wt1 + (size_t)Hsz * Dsz, Dsz, Hsz);
  transpose_cvt<<<dim3(Hsz / 64, Hsz / 64), 256, 0, stream>>>(nw2, wt2, Hsz, Hsz);
  transpose_cvt<<<dim3(Hsz / 64, Hsz / 64), 256, 0, stream>>>(sw2, wt2 + (size_t)Hsz * Hsz, Hsz, Hsz);
  prep_small<<<8, 256, 0, stream>>>(nb1, sb1, nb2, sb2, nw3, sw3, bias1, bias2, w3cat, accN, accS);

  if (big) {
    cvt_f32_to_bf16<<<4096, 256, 0, stream>>>(feat, featb, Msz * Dsz / 4);
    gemm1_k<<<(Msz / 256) * (Nsz / 128), 256, 0, stream>>>(featb, wt1, bias1, h1, Dsz);
  } else {
    gemm_fused<0, true><<<(Msz / 128) * (Nsz / 128), 256, 0, stream>>>(
        feat, wt1, bias1, h1, nullptr, nullptr, nullptr, Dsz, Dsz, 0);
  }
  gemm_fused<1, false><<<(Msz / 128) * (Nsz / 128), 256, 0, stream>>>(
      h1, wt2, bias2, nullptr, w3cat, accN, accS, Hsz, Nsz, Hsz);
  finalize_scan<<<Bsz, 64, 0, stream>>>(accN, accS, nb3, sb3, voff, vscl, rew, cont,
                                        o_rew, o_ret, o_tar, o_cri, o_slo);
}

// Round 4
// 1019.075 us; speedup vs baseline: 1.2439x; 1.2439x over previous
//
#include <hip/hip_runtime.h>
#include <stdint.h>

typedef unsigned short u16;
typedef __attribute__((ext_vector_type(8))) __bf16 bf16x8;
typedef __attribute__((ext_vector_type(8))) u16 u16x8;
typedef __attribute__((ext_vector_type(4))) u16 u16x4;
typedef __attribute__((ext_vector_type(4))) float f32x4;

#define LAM 0.95f
#define DISCOUNT (1.0f - 1.0f / 333.0f)

constexpr int Bsz = 1024, Tsz = 16, Dsz = 5120, Hsz = 1024;
constexpr int Msz = Bsz * Tsz;   // 16384
constexpr int Nsz = 2 * Hsz;     // 2048 (net | slow concat on N)
constexpr int ES = 136;          // epilogue LDS tile stride (u16)

// ---------- helpers ----------
__device__ __forceinline__ u16 f2bf(float x) {
  union { float f; uint32_t u; } un; un.f = x;
  uint32_t u = un.u;
  return (u16)((u + 0x7FFFu + ((u >> 16) & 1u)) >> 16);  // RNE
}
__device__ __forceinline__ void async16(const void* g, void* l) {
  __builtin_amdgcn_global_load_lds(
      (const __attribute__((address_space(1))) uint32_t*)g,
      (__attribute__((address_space(3))) uint32_t*)l, 16, 0, 0);
}

// ---------- prep_all: 4 weight transposes + bias/w3 concat + acc zero, one launch ----------
// blocks 0..1279: nw1 tiles; 1280..2559: sw1; 2560..2815: nw2; 2816..3071: sw2; 3072..3111: misc
__global__ __launch_bounds__(256) void prep_all(
    const float* __restrict__ nw1, const float* __restrict__ sw1,
    const float* __restrict__ nw2, const float* __restrict__ sw2,
    const float* nb1, const float* sb1, const float* nb2, const float* sb2,
    const float* nw3, const float* sw3,
    u16* __restrict__ wt1, u16* __restrict__ wt2,
    float* bias1, float* bias2, float* w3cat, float* accs) {
  const int blk = blockIdx.x;
  const int tid = threadIdx.x;
  if (blk < 3072) {
    const float* src; u16* dst; int K, t;
    if (blk < 1280)      { src = nw1; dst = wt1;                        K = Dsz; t = blk; }
    else if (blk < 2560) { src = sw1; dst = wt1 + (size_t)Hsz * Dsz;    K = Dsz; t = blk - 1280; }
    else if (blk < 2816) { src = nw2; dst = wt2;                        K = Hsz; t = blk - 2560; }
    else                 { src = sw2; dst = wt2 + (size_t)Hsz * Hsz;    K = Hsz; t = blk - 2816; }
    const int ktiles = K / 64;
    const int k0 = (t % ktiles) * 64, n0 = (t / ktiles) * 64;  // N = Hsz always
    __shared__ float tile[64][65];
#pragma unroll
    for (int i = 0; i < 4; ++i) {
      int idx = i * 256 + tid, rr = idx >> 4, c4 = (idx & 15) * 4;
      float4 v = *(const float4*)&src[(size_t)(k0 + rr) * Hsz + n0 + c4];
      tile[rr][c4 + 0] = v.x; tile[rr][c4 + 1] = v.y;
      tile[rr][c4 + 2] = v.z; tile[rr][c4 + 3] = v.w;
    }
    __syncthreads();
#pragma unroll
    for (int i = 0; i < 4; ++i) {
      int idx = i * 256 + tid, rr = idx >> 4, c4 = (idx & 15) * 4;
      u16x4 o;
      o[0] = f2bf(tile[c4 + 0][rr]); o[1] = f2bf(tile[c4 + 1][rr]);
      o[2] = f2bf(tile[c4 + 2][rr]); o[3] = f2bf(tile[c4 + 3][rr]);
      *(u16x4*)&dst[(size_t)(n0 + rr) * K + k0 + c4] = o;
    }
  } else {
    int i = (blk - 3072) * 256 + tid;
    if (i < 1024) { bias1[i] = nb1[i]; bias2[i] = nb2[i]; w3cat[i] = nw3[i]; }
    else if (i < 2048) { bias1[i] = sb1[i - 1024]; bias2[i] = sb2[i - 1024]; w3cat[i] = sw3[i - 1024]; }
    for (int j = i; j < 2 * Msz; j += 40 * 256) accs[j] = 0.f;  // accN|accS contiguous
  }
}

// ---------- fp32 -> bf16, 16B loads + 16B stores ----------
__global__ void cvt_f32_to_bf16(const float* __restrict__ src, u16* __restrict__ dst, int n8) {
  int i = blockIdx.x * 256 + threadIdx.x;
  int stride = gridDim.x * 256;
  for (; i < n8; i += stride) {
    float4 v0 = ((const float4*)src)[2 * i];
    float4 v1 = ((const float4*)src)[2 * i + 1];
    u16x8 o;
    o[0] = f2bf(v0.x); o[1] = f2bf(v0.y); o[2] = f2bf(v0.z); o[3] = f2bf(v0.w);
    o[4] = f2bf(v1.x); o[5] = f2bf(v1.y); o[6] = f2bf(v1.z); o[7] = f2bf(v1.w);
    ((u16x8*)dst)[i] = o;
  }
}

// ---------- GEMM1: 128x128 tile, BK=64, 4 waves of 64x64 (Round-2 structure) ----------
// Out[m][n] = bf16(silu(A·B^T + bias)); operand-swapped MFMA:
// lane value (a,b,rr): row m = wm+a*16+(lane&15), col n = wn+b*16+(lane>>4)*4+rr
template <bool A_F32>
__global__ __launch_bounds__(256) void gemm1_k(
    const void* __restrict__ Ap, const u16* __restrict__ Bp,
    const float* __restrict__ bias, u16* __restrict__ Out, int K) {
  __shared__ __align__(16) u16 smem[128 * ES];  // >= 16384 staging u16s
  u16* ldsA = smem;
  u16* ldsB = smem + 8192;

  const int tid = threadIdx.x;
  const int lane = tid & 63;
  const int wv = tid >> 6;
  const int wm = (wv >> 1) << 6;
  const int wn = (wv & 1) << 6;
  const int lm = lane & 15, lq = lane >> 4, l7 = lane & 7;

  // XCD-pinned supertile: xcd = blk&7 owns 16 M-tiles x 16 N-tiles, 8x8 quads
  const int blk = blockIdx.x;
  const int xcd = blk & 7;
  const int l = blk >> 3;
  const int quad = l >> 6;
  const int mi = l & 7, ni = (l >> 3) & 7;
  const int mt = xcd * 16 + ((quad & 1) << 3) + mi;
  const int nt = ((quad >> 1) << 3) + ni;
  const int m0 = mt << 7, n0 = nt << 7;

  const u16* bsrc[4];
  const float* asrcf[4];
  const u16* asrcb[4];
  u16* ldsAd[4];
  u16* ldsBd[4];
#pragma unroll
  for (int i = 0; i < 4; ++i) {
    int cid = i * 256 + tid;
    int row = cid >> 3, ch = cid & 7;
    int kp = ch ^ (row & 7);
    bsrc[i] = Bp + (size_t)(n0 + row) * K + kp * 8;
    if (A_F32) asrcf[i] = (const float*)Ap + (size_t)(m0 + row) * K + kp * 8;
    else       asrcb[i] = (const u16*)Ap + (size_t)(m0 + row) * K + kp * 8;
    ldsAd[i] = &ldsA[cid * 8];
    ldsBd[i] = &ldsB[cid * 8];
  }

  int rA[4], rB[4];
#pragma unroll
  for (int t = 0; t < 4; ++t) {
    rA[t] = (wm + t * 16 + lm) * 64;
    rB[t] = (wn + t * 16 + lm) * 64;
  }

  f32x4 acc[4][4];
#pragma unroll
  for (int a = 0; a < 4; ++a)
#pragma unroll
    for (int b = 0; b < 4; ++b) acc[a][b] = f32x4{0.f, 0.f, 0.f, 0.f};

  for (int kt = 0; kt < K; kt += 64) {
#pragma unroll
    for (int i = 0; i < 4; ++i) async16(bsrc[i] + kt, ldsBd[i]);
    if (A_F32) {
      float4 v0[4], v1[4];
#pragma unroll
      for (int i = 0; i < 4; ++i) {
        const float* p = asrcf[i] + kt;
        v0[i] = *(const float4*)p;
        v1[i] = *(const float4*)(p + 4);
      }
#pragma unroll
      for (int i = 0; i < 4; ++i) {
        u16x8 pk;
        pk[0] = f2bf(v0[i].x); pk[1] = f2bf(v0[i].y); pk[2] = f2bf(v0[i].z); pk[3] = f2bf(v0[i].w);
        pk[4] = f2bf(v1[i].x); pk[5] = f2bf(v1[i].y); pk[6] = f2bf(v1[i].z); pk[7] = f2bf(v1[i].w);
        *(u16x8*)ldsAd[i] = pk;
      }
    } else {
#pragma unroll
      for (int i = 0; i < 4; ++i) async16(asrcb[i] + kt, ldsAd[i]);
    }
    __syncthreads();
#pragma unroll
    for (int ks = 0; ks < 2; ++ks) {
      const int ck = ((ks << 2) + lq) ^ l7;
      bf16x8 af[4], bfr[4];
#pragma unroll
      for (int t = 0; t < 4; ++t) af[t] = *(const bf16x8*)&ldsA[rA[t] + ck * 8];
#pragma unroll
      for (int t = 0; t < 4; ++t) bfr[t] = *(const bf16x8*)&ldsB[rB[t] + ck * 8];
#pragma unroll
      for (int a = 0; a < 4; ++a)
#pragma unroll
        for (int b = 0; b < 4; ++b)
          acc[a][b] = __builtin_amdgcn_mfma_f32_16x16x32_bf16(bfr[b], af[a], acc[a][b], 0, 0, 0);
    }
    __syncthreads();
  }

  // epilogue: bias+silu -> LDS tile -> coalesced 16B stores
#pragma unroll
  for (int a = 0; a < 4; ++a) {
    int ml = wm + a * 16 + lm;
#pragma unroll
    for (int b = 0; b < 4; ++b) {
      int nb = wn + b * 16 + lq * 4;
      u16x4 pk;
#pragma unroll
      for (int rr = 0; rr < 4; ++rr) {
        float v = acc[a][b][rr] + bias[n0 + nb + rr];
        v = v * (1.0f / (1.0f + __expf(-v)));
        pk[rr] = f2bf(v);
      }
      *(u16x4*)&smem[ml * ES + nb] = pk;
    }
  }
  __syncthreads();
#pragma unroll
  for (int i = 0; i < 8; ++i) {
    int r = i * 16 + (tid >> 4);
    int c = (tid & 15) * 8;
    u16x8 vv = *(const u16x8*)&smem[r * ES + c];
    *(u16x8*)&Out[(size_t)(m0 + r) * Nsz + n0 + c] = vv;
  }
}

// ---------- GEMM2 + fused w3 head: 128x128 tile, BK=128 (8 iters), 64KB LDS ----------
__global__ __launch_bounds__(256) void gemm2_k(
    const u16* __restrict__ Ap, const u16* __restrict__ Bp,
    const float* __restrict__ bias, const float* __restrict__ w3cat,
    float* __restrict__ accN, float* __restrict__ accS) {
  __shared__ __align__(16) u16 ldsA[128 * 128];  // 32 KB
  __shared__ __align__(16) u16 ldsB[128 * 128];  // 32 KB

  const int tid = threadIdx.x;
  const int lane = tid & 63;
  const int wv = tid >> 6;
  const int wm = (wv >> 1) << 6;
  const int wn = (wv & 1) << 6;
  const int lm = lane & 15, lq = lane >> 4;

  const int blk = blockIdx.x;
  const int xcd = blk & 7;
  const int l = blk >> 3;
  const int quad = l >> 6;
  const int mi = l & 7, ni = (l >> 3) & 7;
  const int mt = xcd * 16 + ((quad & 1) << 3) + mi;
  const int nt = ((quad >> 1) << 3) + ni;
  const int m0 = mt << 7, n0 = nt << 7;
  const int a_off = (n0 >= Hsz) ? Hsz : 0;

  // staging: 2048 16B chunks per operand (8/thread); 16-chunk XOR swizzle per 256B row
  uint32_t aoff[8], boff[8];
  u16 *ldsAd[8], *ldsBd[8];
#pragma unroll
  for (int i = 0; i < 8; ++i) {
    int cid = i * 256 + tid;
    int row = cid >> 4, ch = cid & 15;
    int kp = ch ^ (row & 15);
    aoff[i] = (uint32_t)(m0 + row) * Nsz + a_off + kp * 8;
    boff[i] = (uint32_t)(n0 + row) * Hsz + kp * 8;
    ldsAd[i] = &ldsA[cid * 8];
    ldsBd[i] = &ldsB[cid * 8];
  }

  f32x4 acc[4][4];
#pragma unroll
  for (int a = 0; a < 4; ++a)
#pragma unroll
    for (int b = 0; b < 4; ++b) acc[a][b] = f32x4{0.f, 0.f, 0.f, 0.f};

  for (int kt = 0; kt < Hsz; kt += 128) {
#pragma unroll
    for (int i = 0; i < 8; ++i) async16(Bp + boff[i] + kt, ldsBd[i]);
#pragma unroll
    for (int i = 0; i < 8; ++i) async16(Ap + aoff[i] + kt, ldsAd[i]);
    __syncthreads();
#pragma unroll
    for (int ks = 0; ks < 4; ++ks) {
      const int ck = ((ks << 2) + lq) ^ lm;  // stored chunk for logical k-chunk ks*4+lq (row&15==lm)
      bf16x8 af[4], bfr[4];
#pragma unroll
      for (int t = 0; t < 4; ++t) af[t] = *(const bf16x8*)&ldsA[(wm + t * 16 + lm) * 128 + ck * 8];
#pragma unroll
      for (int t = 0; t < 4; ++t) bfr[t] = *(const bf16x8*)&ldsB[(wn + t * 16 + lm) * 128 + ck * 8];
#pragma unroll
      for (int a = 0; a < 4; ++a)
#pragma unroll
        for (int b = 0; b < 4; ++b)
          acc[a][b] = __builtin_amdgcn_mfma_f32_16x16x32_bf16(bfr[b], af[a], acc[a][b], 0, 0, 0);
    }
    __syncthreads();
  }

  // fused head: dot silu(pre-act) with w3 slice, reduce over lq halves, atomicAdd per row
  float pr[4] = {0.f, 0.f, 0.f, 0.f};
#pragma unroll
  for (int a = 0; a < 4; ++a) {
#pragma unroll
    for (int b = 0; b < 4; ++b) {
      int nb = n0 + wn + b * 16 + lq * 4;
#pragma unroll
      for (int rr = 0; rr < 4; ++rr) {
        float v = acc[a][b][rr] + bias[nb + rr];
        v = v * (1.0f / (1.0f + __expf(-v)));
        pr[a] += v * w3cat[nb + rr];
      }
    }
  }
  float* accp = (n0 < Hsz) ? accN : accS;
#pragma unroll
  for (int a = 0; a < 4; ++a) {
    pr[a] += __shfl_xor(pr[a], 16);
    pr[a] += __shfl_xor(pr[a], 32);
    if (lq == 0) atomicAdd(&accp[m0 + wm + a * 16 + lm], pr[a]);
  }
}

// ---------- finalize + per-batch lambda-return scan ----------
__global__ void finalize_scan(const float* __restrict__ accN, const float* __restrict__ accS,
                              const float* __restrict__ nb3, const float* __restrict__ sb3,
                              const float* __restrict__ voff, const float* __restrict__ vscl,
                              const float* __restrict__ rew, const float* __restrict__ cont,
                              float* __restrict__ o_rew, float* __restrict__ o_ret,
                              float* __restrict__ o_tar, float* __restrict__ o_cri,
                              float* __restrict__ o_slo) {
  __shared__ float star[Tsz], srew[Tsz], scont[Tsz];
  int b = blockIdx.x;
  int t = threadIdx.x;
  if (t < Tsz) {
    int m = b * Tsz + t;
    float c = accN[m] + nb3[0];
    float s = accS[m] + sb3[0];
    float tv = s * vscl[0] + voff[0];
    o_cri[m] = c; o_slo[m] = s; o_tar[m] = tv;
    float rw = rew[m];
    o_rew[m] = rw;
    star[t] = tv; srew[t] = rw; scont[t] = cont[m];
  }
  __syncthreads();
  if (t == 0) {
    float carry = star[Tsz - 1];
    for (int k = Tsz - 2; k >= 0; --k) {
      float d = scont[k + 1] * DISCOUNT;
      carry = srew[k + 1] + (1.0f - LAM) * d * star[k + 1] + d * LAM * carry;
      o_ret[b * (Tsz - 1) + k] = carry;
    }
  }
}

// ---------- workspace layout ----------
constexpr size_t WT1_OFF = 0;
constexpr size_t WT1_BYTES = (size_t)Nsz * Dsz * 2;
constexpr size_t WT2_OFF = WT1_OFF + WT1_BYTES;
constexpr size_t WT2_BYTES = (size_t)Nsz * Hsz * 2;
constexpr size_t B1_OFF = WT2_OFF + WT2_BYTES;
constexpr size_t B2_OFF = B1_OFF + 8192;
constexpr size_t W3_OFF = B2_OFF + 8192;
constexpr size_t ACCN_OFF = W3_OFF + 8192;
constexpr size_t ACCS_OFF = ACCN_OFF + (size_t)Msz * 4;
constexpr size_t H1_OFF = ACCS_OFF + (size_t)Msz * 4;
constexpr size_t H_BYTES = (size_t)Msz * Nsz * 2;
constexpr size_t FEATB_OFF = H1_OFF + H_BYTES;
constexpr size_t FEATB_BYTES = (size_t)Msz * Dsz * 2;
constexpr size_t NEED_BIG = FEATB_OFF + FEATB_BYTES;

extern "C" void kernel_launch(void* const* d_in, const int* in_sizes, int n_in,
                              void* d_out, int out_size, void* d_ws, size_t ws_size,
                              hipStream_t stream) {
  const float* feat = (const float*)d_in[0];
  const float* rew  = (const float*)d_in[1];
  const float* cont = (const float*)d_in[2];
  const float* nw1  = (const float*)d_in[3];
  const float* nb1  = (const float*)d_in[4];
  const float* nw2  = (const float*)d_in[5];
  const float* nb2  = (const float*)d_in[6];
  const float* nw3  = (const float*)d_in[7];
  const float* nb3  = (const float*)d_in[8];
  const float* sw1  = (const float*)d_in[9];
  const float* sb1  = (const float*)d_in[10];
  const float* sw2  = (const float*)d_in[11];
  const float* sb2  = (const float*)d_in[12];
  const float* sw3  = (const float*)d_in[13];
  const float* sb3  = (const float*)d_in[14];
  const float* voff = (const float*)d_in[15];
  const float* vscl = (const float*)d_in[16];

  char* ws = (char*)d_ws;
  u16* wt1 = (u16*)(ws + WT1_OFF);
  u16* wt2 = (u16*)(ws + WT2_OFF);
  float* bias1 = (float*)(ws + B1_OFF);
  float* bias2 = (float*)(ws + B2_OFF);
  float* w3cat = (float*)(ws + W3_OFF);
  float* accN = (float*)(ws + ACCN_OFF);
  float* accS = (float*)(ws + ACCS_OFF);
  u16* h1 = (u16*)(ws + H1_OFF);
  u16* featb = (u16*)(ws + FEATB_OFF);
  const bool big = ws_size >= NEED_BIG;

  float* out = (float*)d_out;
  float* o_rew = out;
  float* o_ret = out + 16384;
  float* o_tar = out + 31744;
  float* o_cri = out + 48128;
  float* o_slo = out + 64512;

  prep_all<<<3112, 256, 0, stream>>>(nw1, sw1, nw2, sw2, nb1, sb1, nb2, sb2, nw3, sw3,
                                     wt1, wt2, bias1, bias2, w3cat, accN);

  const int gemm_grid = (Msz / 128) * (Nsz / 128);  // 2048
  if (big) {
    cvt_f32_to_bf16<<<4096, 256, 0, stream>>>(feat, featb, Msz * Dsz / 8);
    gemm1_k<false><<<gemm_grid, 256, 0, stream>>>(featb, wt1, bias1, h1, Dsz);
  } else {
    gemm1_k<true><<<gemm_grid, 256, 0, stream>>>(feat, wt1, bias1, h1, Dsz);
  }
  gemm2_k<<<gemm_grid, 256, 0, stream>>>(h1, wt2, bias2, w3cat, accN, accS);
  finalize_scan<<<Bsz, 64, 0, stream>>>(accN, accS, nb3, sb3, voff, vscl, rew, cont,
                                        o_rew, o_ret, o_tar, o_cri, o_slo);
}